// Round 5
// baseline (343.916 us; speedup 1.0000x reference)
//
#include <hip/hip_runtime.h>

// IF spiking neuron, T=8 over (B=32, T=8, CHW=200704) fp32. Streaming:
// 205 MB in + 205 MB out. Loads are TEMPORAL (x was just re-written by the
// harness restore copy -> mostly resident in 256 MiB MALL; nt would forfeit
// those hits). Stores stay nontemporal (write-once, no reuse).
// Burst-issue all 16 loads, then recurrence + 16 nt stores.

typedef float v4f __attribute__((ext_vector_type(4)));

#define CHW_VEC 50176   // 64*56*56 / 4
#define TSTEPS 8
#define NBATCH 32
#define BLK 256
#define VPT 2           // vec4s per thread

__global__ __launch_bounds__(BLK) void IF_33122787787165_kernel(
    const v4f* __restrict__ x, v4f* __restrict__ out) {
    const unsigned i0 = blockIdx.x * (BLK * VPT) + threadIdx.x;  // vec4 idx in CHW
    const unsigned b = blockIdx.y;
    const unsigned base = b * (TSTEPS * CHW_VEC) + i0;           // < 2^31 vec4

    // Phase 1: burst-issue all loads (temporal -> MALL hits).
    v4f xt[TSTEPS][VPT];
#pragma unroll
    for (int t = 0; t < TSTEPS; ++t)
#pragma unroll
        for (int v = 0; v < VPT; ++v)
            xt[t][v] = x[base + (unsigned)t * CHW_VEC + v * BLK];

    // Phase 2: recurrence + nontemporal stores.
    v4f mem[VPT];
#pragma unroll
    for (int v = 0; v < VPT; ++v) mem[v] = (v4f)(0.0f);

#pragma unroll
    for (int t = 0; t < TSTEPS; ++t) {
#pragma unroll
        for (int v = 0; v < VPT; ++v) {
            v4f m = mem[v] + xt[t][v];
            v4f s;
            s.x = (m.x > 1.0f) ? 1.0f : 0.0f;
            s.y = (m.y > 1.0f) ? 1.0f : 0.0f;
            s.z = (m.z > 1.0f) ? 1.0f : 0.0f;
            s.w = (m.w > 1.0f) ? 1.0f : 0.0f;
            m.x = (m.x > 1.0f) ? 0.0f : m.x;
            m.y = (m.y > 1.0f) ? 0.0f : m.y;
            m.z = (m.z > 1.0f) ? 0.0f : m.z;
            m.w = (m.w > 1.0f) ? 0.0f : m.w;
            mem[v] = m;
            __builtin_nontemporal_store(s, &out[base + (unsigned)t * CHW_VEC + v * BLK]);
        }
    }
}

extern "C" void kernel_launch(void* const* d_in, const int* in_sizes, int n_in,
                              void* d_out, int out_size, void* d_ws, size_t ws_size,
                              hipStream_t stream) {
    const v4f* x = (const v4f*)d_in[0];
    v4f* out = (v4f*)d_out;
    dim3 grid(CHW_VEC / (BLK * VPT), NBATCH);  // 98 x 32 blocks
    IF_33122787787165_kernel<<<grid, BLK, 0, stream>>>(x, out);
}

// Round 6
// 320.155 us; speedup vs baseline: 1.0742x; 1.0742x over previous
//
#include <hip/hip_runtime.h>

// IF spiking neuron, T=8 over (B=32, T=8, CHW=200704) fp32. Streaming,
// zero-reuse: 205 MB in + 205 MB out. Nontemporal BOTH directions (R5 showed
// temporal loads cost +22us: poison fill evicts x from MALL anyway, temporal
// just churns L2 against the store stream). VPT=1: MLP is already ample;
// more blocks (6272, 24.5/CU) -> finer channel interleave, smoother tail.

typedef float v4f __attribute__((ext_vector_type(4)));

#define CHW_VEC 50176   // 64*56*56 / 4
#define TSTEPS 8
#define NBATCH 32
#define BLK 256

__global__ __launch_bounds__(BLK) void IF_33122787787165_kernel(
    const v4f* __restrict__ x, v4f* __restrict__ out) {
    const unsigned i = blockIdx.x * BLK + threadIdx.x;   // vec4 idx in CHW
    const unsigned b = blockIdx.y;
    const unsigned base = b * (TSTEPS * CHW_VEC) + i;

    v4f mem = (v4f)(0.0f);
#pragma unroll
    for (int t = 0; t < TSTEPS; ++t) {
        const v4f xt = __builtin_nontemporal_load(&x[base + (unsigned)t * CHW_VEC]);
        v4f m = mem + xt;
        v4f s;
        s.x = (m.x > 1.0f) ? 1.0f : 0.0f;
        s.y = (m.y > 1.0f) ? 1.0f : 0.0f;
        s.z = (m.z > 1.0f) ? 1.0f : 0.0f;
        s.w = (m.w > 1.0f) ? 1.0f : 0.0f;
        m.x = (m.x > 1.0f) ? 0.0f : m.x;
        m.y = (m.y > 1.0f) ? 0.0f : m.y;
        m.z = (m.z > 1.0f) ? 0.0f : m.z;
        m.w = (m.w > 1.0f) ? 0.0f : m.w;
        mem = m;
        __builtin_nontemporal_store(s, &out[base + (unsigned)t * CHW_VEC]);
    }
}

extern "C" void kernel_launch(void* const* d_in, const int* in_sizes, int n_in,
                              void* d_out, int out_size, void* d_ws, size_t ws_size,
                              hipStream_t stream) {
    const v4f* x = (const v4f*)d_in[0];
    v4f* out = (v4f*)d_out;
    dim3 grid(CHW_VEC / BLK, NBATCH);  // 196 x 32 blocks
    IF_33122787787165_kernel<<<grid, BLK, 0, stream>>>(x, out);
}